// Round 6
// baseline (242.499 us; speedup 1.0000x reference)
//
#include <hip/hip_runtime.h>

#define B_ROWS 8192
#define DIN    1024
#define UNITS  1024
#define KTOT   2048   // DIN + UNITS
#define NCOLS  4096   // 4*UNITS
#define BM 256
#define BN 256
#define BK 64
#define NT (KTOT / BK)    // 32 K-tiles
#define NITER (NT / 2)    // 16 iterations, 2 K-tiles each

typedef __attribute__((ext_vector_type(8))) short bf16x8;
typedef __attribute__((ext_vector_type(4))) float f32x4;
typedef __attribute__((ext_vector_type(4))) unsigned short u16x4;

#define AS1(p) ((const __attribute__((address_space(1))) void*)(p))
#define AS3(p) ((__attribute__((address_space(3))) void*)(p))

__device__ inline unsigned short f2bf(float v) {
  union { float f; unsigned int u; } un; un.f = v;
  unsigned int r = un.u + 0x7FFFu + ((un.u >> 16) & 1u);   // RNE
  return (unsigned short)(r >> 16);
}

// XOR-swizzle within each 64-element K-tile group, baked into the STORED
// global layout (rule #21: global_load_lds stays linear; ds_read applies
// the same XOR).
__device__ inline int swz_col(int c, int r) {
  return (c & ~63) | ((c & 63) ^ ((r & 7) << 3));
}

__device__ inline float sigmoid_f(float x) { return 1.0f / (1.0f + __expf(-x)); }
__device__ inline float tanh_f(float x)    { return 1.0f - 2.0f / (1.0f + __expf(2.0f * x)); }

// Inline-asm LDS read: opaque to the compiler's LDS-DMA hazard tracking so it
// cannot insert its own vmcnt drains before each phase (the round-4/5 null).
// Ordering vs MFMA is re-established manually: lgkmcnt(0)+sched_barrier(0)
// before every MFMA cluster (rule #18).
__device__ __forceinline__ bf16x8 lds_rd_b128(unsigned addr) {
  bf16x8 r;
  asm volatile("ds_read_b128 %0, %1" : "=v"(r) : "v"(addr));
  return r;
}

// ---------------- prep A: A_bf16[row][k] = masked x (k<1024) | masked h (k>=1024) ----
__global__ void prep_a_kernel(const float* __restrict__ x, const float* __restrict__ h,
                              const float* __restrict__ dp, const float* __restrict__ rdp,
                              unsigned short* __restrict__ A) {
  const int n4 = (B_ROWS * DIN) / 4;
  const float sc = 1.0f / 0.9f;
  for (int i = blockIdx.x * blockDim.x + threadIdx.x; i < n4; i += gridDim.x * blockDim.x) {
    float4 xv = reinterpret_cast<const float4*>(x)[i];
    float4 uv = reinterpret_cast<const float4*>(dp)[i];
    float4 hv = reinterpret_cast<const float4*>(h)[i];
    float4 rv = reinterpret_cast<const float4*>(rdp)[i];
    u16x4 xa, ha;
    xa.x = f2bf(uv.x >= 0.1f ? xv.x * sc : 0.0f);
    xa.y = f2bf(uv.y >= 0.1f ? xv.y * sc : 0.0f);
    xa.z = f2bf(uv.z >= 0.1f ? xv.z * sc : 0.0f);
    xa.w = f2bf(uv.w >= 0.1f ? xv.w * sc : 0.0f);
    ha.x = f2bf(rv.x >= 0.1f ? hv.x * sc : 0.0f);
    ha.y = f2bf(rv.y >= 0.1f ? hv.y * sc : 0.0f);
    ha.z = f2bf(rv.z >= 0.1f ? hv.z * sc : 0.0f);
    ha.w = f2bf(rv.w >= 0.1f ? hv.w * sc : 0.0f);
    int e = i * 4;
    int row = e >> 10;
    int col = e & 1023;
    int csw = swz_col(col, row);
    *reinterpret_cast<u16x4*>(&A[(size_t)row * KTOT + csw]) = xa;
    *reinterpret_cast<u16x4*>(&A[(size_t)row * KTOT + DIN + csw]) = ha;
  }
}

// ---------------- prep B: Bt[n][k] (bf16, N-major), 64-unit gate interleave ---------
// source col c = g*1024 + m  ->  n = (m>>6)*256 + g*64 + (m&63)
__global__ void prep_b_kernel(const float* __restrict__ kern, const float* __restrict__ rkern,
                              const float* __restrict__ kdp, const float* __restrict__ rkdp,
                              unsigned short* __restrict__ Bt) {
  __shared__ float tile[32][33];
  const int c0 = blockIdx.x * 32;
  const int k0 = blockIdx.y * 32;
  const float sc = 1.0f / 0.95f;
  const float* W; const float* U; int kr;
  if (k0 < DIN) { W = kern;  U = kdp;  kr = k0; }
  else          { W = rkern; U = rkdp; kr = k0 - DIN; }
  const int tx = threadIdx.x, ty = threadIdx.y;
  #pragma unroll
  for (int i = 0; i < 4; ++i) {
    int kk = ty + i * 8;
    size_t off = (size_t)(kr + kk) * NCOLS + c0 + tx;
    float wv = W[off];
    float uv = U[off];
    tile[kk][tx] = (uv >= 0.05f) ? wv * sc : 0.0f;
  }
  __syncthreads();
  const int g  = c0 >> 10;
  const int m0 = c0 & 1023;
  #pragma unroll
  for (int i = 0; i < 4; ++i) {
    int cc = ty + i * 8;
    int m = m0 + cc;
    int n = (m >> 6) * 256 + g * 64 + (m & 63);
    int kst = swz_col(k0 + tx, n);
    Bt[(size_t)n * KTOT + kst] = f2bf(tile[tx][cc]);
  }
}

// ---------------- 256x256 8-phase GEMM, asm ds_read + counted vmcnt -----------------
// One half-tile (16KB, 2 global_load_lds/thread) staged per phase; 7 halves
// (14 loads) in flight steady-state; vmcnt(6)=3 halves left at P4/P8 drains
// exactly the 4 halves (8 loads) needed next. Last iteration: vmcnt(0)
// (its stages are skipped). Schedule as hand-verified in round 5.

#define FENCE() asm volatile("" ::: "memory")
#define SBAR()  do { FENCE(); __builtin_amdgcn_s_barrier(); FENCE(); } while (0)

#define LOAD_A(BUF, MH) do { \
  const unsigned ab_ = ldsbase + (unsigned)((BUF) * 65536); \
  _Pragma("unroll") for (int f_ = 0; f_ < 4; ++f_) { \
    const int row_ = ((MH) * 4 + f_) * 32 + wm * 16 + r15; \
    _Pragma("unroll") for (int ks_ = 0; ks_ < 2; ++ks_) \
      a[f_ * 2 + ks_] = lds_rd_b128(ab_ + (unsigned)((row_ * 64 + ((ks_ * 32 + kh * 8) ^ sw)) * 2)); \
  } } while (0)

#define LOAD_B(BUF, NH) do { \
  const unsigned bb_ = ldsbase + (unsigned)((BUF) * 65536 + 32768); \
  _Pragma("unroll") for (int g_ = 0; g_ < 2; ++g_) { \
    const int row_ = ((NH) * 2 + g_) * 64 + wn * 16 + r15; \
    _Pragma("unroll") for (int ks_ = 0; ks_ < 2; ++ks_) \
      b[((NH) * 2 + g_) * 2 + ks_] = lds_rd_b128(bb_ + (unsigned)((row_ * 64 + ((ks_ * 32 + kh * 8) ^ sw)) * 2)); \
  } } while (0)

// lgkmcnt(0) + sched_barrier(0) re-establishes the ds_read->MFMA dependency the
// asm reads hid from the compiler (rule #18), then the MFMA cluster runs at
// raised priority (T5).
#define MMA_QUAD(MH, NH) do { \
  asm volatile("s_waitcnt lgkmcnt(0)" ::: "memory"); \
  __builtin_amdgcn_sched_barrier(0); \
  __builtin_amdgcn_s_setprio(1); \
  _Pragma("unroll") for (int f_ = 0; f_ < 4; ++f_) \
    _Pragma("unroll") for (int g_ = 0; g_ < 2; ++g_) \
      _Pragma("unroll") for (int ks_ = 0; ks_ < 2; ++ks_) \
        acc[(MH) * 4 + f_][(NH) * 2 + g_] = __builtin_amdgcn_mfma_f32_16x16x32_bf16( \
            a[f_ * 2 + ks_], b[((NH) * 2 + g_) * 2 + ks_], acc[(MH) * 4 + f_][(NH) * 2 + g_], 0, 0, 0); \
  __builtin_amdgcn_s_setprio(0); \
  } while (0)

#define VM_WAIT(T) do { \
  if ((T) < NITER - 1) { asm volatile("s_waitcnt vmcnt(6)" ::: "memory"); } \
  else                 { asm volatile("s_waitcnt vmcnt(0)" ::: "memory"); } \
  __builtin_amdgcn_sched_barrier(0); \
  } while (0)

__global__ __launch_bounds__(512, 2) void lstm_gemm_kernel(
    const unsigned short* __restrict__ A,
    const unsigned short* __restrict__ Bt,
    const float* __restrict__ bias,
    const float* __restrict__ c_in,
    float* __restrict__ out_h,
    float* __restrict__ out_c) {
  __shared__ __align__(16) unsigned char smem[131072];

  const int tid  = threadIdx.x;
  const int lane = tid & 63;
  const int wid  = tid >> 6;     // 0..7
  const int wm   = wid & 1;      // M-wave (16-row interleave)
  const int wn   = wid >> 1;     // 0..3  (16-col interleave)
  const int bm   = blockIdx.x >> 4;   // 32 row-blocks
  const int bn   = blockIdx.x & 15;   // 16 col-blocks
  const int brow = bm * BM;
  const int bnrow = bn * BN;
  const int r15  = lane & 15;
  const int kh   = lane >> 4;
  const int sw   = (r15 & 7) << 3;
  const unsigned ldsbase =
      (unsigned)(size_t)((__attribute__((address_space(3))) unsigned char*)smem);

  f32x4 acc[8][4];
  const f32x4 zero4 = {0.0f, 0.0f, 0.0f, 0.0f};
  #pragma unroll
  for (int i = 0; i < 8; ++i)
    #pragma unroll
    for (int j = 0; j < 4; ++j) acc[i][j] = zero4;
  bf16x8 a[8], b[8];

  // one stage = one 16KB half-tile = 2 x global_load_lds(16B) per thread
  auto stageA = [&](int buf, int half, int kt) {
    if (kt >= NT) return;
    const int k0 = kt * BK;
    #pragma unroll
    for (int r = 0; r < 2; ++r) {
      const int rowb = half * 128 + r * 64 + wid * 8;   // wave-uniform
      const unsigned short* g = A + (size_t)(brow + rowb + (lane >> 3)) * KTOT + k0 + (lane & 7) * 8;
      __builtin_amdgcn_global_load_lds(AS1(g), AS3(smem + buf * 65536 + rowb * 128), 16, 0, 0);
    }
  };
  auto stageB = [&](int buf, int half, int kt) {
    if (kt >= NT) return;
    const int k0 = kt * BK;
    #pragma unroll
    for (int r = 0; r < 2; ++r) {
      const int rowb = half * 128 + r * 64 + wid * 8;
      const unsigned short* g = Bt + (size_t)(bnrow + rowb + (lane >> 3)) * KTOT + k0 + (lane & 7) * 8;
      __builtin_amdgcn_global_load_lds(AS1(g), AS3(smem + buf * 65536 + 32768 + rowb * 128), 16, 0, 0);
    }
  };

  // prologue: buf0 tile0 all 4 halves FIRST (drained by vmcnt(6)), then 3 of buf1 tile1
  stageA(0, 0, 0); stageB(0, 0, 0); stageB(0, 1, 0); stageA(0, 1, 0);
  stageA(1, 0, 1); stageB(1, 0, 1); stageB(1, 1, 1);
  asm volatile("s_waitcnt vmcnt(6)" ::: "memory");
  __builtin_amdgcn_sched_barrier(0);
  SBAR();

  #pragma unroll 1
  for (int t = 0; t < NITER; ++t) {
    const int kx = 2 * t + 2;      // next buf0 tile
    const int ky = 2 * t + 3;      // next buf1 tile
    // P1
    LOAD_A(0, 0); LOAD_B(0, 0);
    stageA(1, 1, 2 * t + 1);
    SBAR();
    MMA_QUAD(0, 0);
    SBAR();
    // P2
    LOAD_B(0, 1);
    stageA(0, 0, kx);
    SBAR();
    MMA_QUAD(0, 1);
    SBAR();
    // P3
    LOAD_A(0, 1);
    stageB(0, 0, kx);
    SBAR();
    MMA_QUAD(1, 0);
    SBAR();
    // P4
    stageB(0, 1, kx);
    SBAR();
    MMA_QUAD(1, 1);
    VM_WAIT(t);
    SBAR();
    // P5
    LOAD_A(1, 0); LOAD_B(1, 0);
    stageA(0, 1, kx);
    SBAR();
    MMA_QUAD(0, 0);
    SBAR();
    // P6
    LOAD_B(1, 1);
    stageA(1, 0, ky);
    SBAR();
    MMA_QUAD(0, 1);
    SBAR();
    // P7
    LOAD_A(1, 1);
    stageB(1, 0, ky);
    SBAR();
    MMA_QUAD(1, 0);
    SBAR();
    // P8
    stageB(1, 1, ky);
    SBAR();
    MMA_QUAD(1, 1);
    VM_WAIT(t);
    SBAR();
  }

  // ---- in-register epilogue: acc[f][g] = gate g of unit bn*64+wn*16+r15 ----
  const int unit = bn * 64 + wn * 16 + r15;
  const float b0 = bias[unit];
  const float b1 = bias[1024 + unit];
  const float b2 = bias[2048 + unit];
  const float b3 = bias[3072 + unit];
  #pragma unroll
  for (int f = 0; f < 8; ++f) {
    const int row0 = brow + f * 32 + wm * 16 + kh * 4;
    #pragma unroll
    for (int j = 0; j < 4; ++j) {
      size_t gidx = (size_t)(row0 + j) * UNITS + unit;
      float zi = acc[f][0][j] + b0;
      float zf = acc[f][1][j] + b1;
      float zc = acc[f][2][j] + b2;
      float zo = acc[f][3][j] + b3;
      float ig = sigmoid_f(zi);
      float fg = sigmoid_f(zf);
      float gg = tanh_f(zc);
      float og = sigmoid_f(zo);
      float cn = fg * c_in[gidx] + ig * gg;
      float hn = og * tanh_f(cn);
      out_h[gidx] = hn;
      out_c[gidx] = cn;
    }
  }
}

extern "C" void kernel_launch(void* const* d_in, const int* in_sizes, int n_in,
                              void* d_out, int out_size, void* d_ws, size_t ws_size,
                              hipStream_t stream) {
  const float* x     = (const float*)d_in[0];
  const float* h     = (const float*)d_in[1];
  const float* c     = (const float*)d_in[2];
  const float* kern  = (const float*)d_in[3];
  const float* rkern = (const float*)d_in[4];
  const float* bias  = (const float*)d_in[5];
  const float* dp    = (const float*)d_in[6];
  const float* rdp   = (const float*)d_in[7];
  const float* kdp   = (const float*)d_in[8];
  const float* rkdp  = (const float*)d_in[9];

  unsigned short* Abf  = (unsigned short*)d_ws;                       // 32MB
  unsigned short* Btbf = Abf + (size_t)B_ROWS * KTOT;                 // 16MB

  float* out_h = (float*)d_out;
  float* out_c = out_h + (size_t)B_ROWS * UNITS;

  prep_a_kernel<<<2048, 256, 0, stream>>>(x, h, dp, rdp, Abf);
  prep_b_kernel<<<dim3(128, 64), dim3(32, 8), 0, stream>>>(kern, rkern, kdp, rkdp, Btbf);
  lstm_gemm_kernel<<<512, 512, 0, stream>>>(Abf, Btbf, bias, c, out_h, out_c);
}